// Round 5
// baseline (5216.880 us; speedup 1.0000x reference)
//
#include <hip/hip_runtime.h>

#define B_  256
#define T_  512
#define F_  64
#define H_  1024
#define TL_ 64

typedef _Float16 half8 __attribute__((ext_vector_type(8)));
typedef float   floatx4 __attribute__((ext_vector_type(4)));
typedef unsigned long long ull;

#define MFMA(a, b, c) __builtin_amdgcn_mfma_f32_16x16x32_f16(a, b, c, 0, 0, 0)

// ws layout (bytes)
#define WF_E   0UL          // W_hh enc fragments: 3*64*32 chunks * 1024B
#define WF_D   6291456UL    // W_hh dec fragments
#define WF_I   12582912UL   // W_ih enc fragments: 3*64*2 chunks * 1024B
#define HP     12976128UL   // h planes: [2 parity][hi fp16 512KB]
#define PSTR   524288UL     // parity stride
#define PB     15073280UL   // fc partials: [2][64 jg][256 rows] f32
#define BARS   15204352UL   // 16 group counters, 128B apart
// h plane (fragment-major fp16): [rg 16][kb 32][lane 64][16B]; slab 32KB/rg;
// in the r15 split, block (rg,cb) owns the contiguous 1KB at
// rg*32768 + cb*1024 (exactly LDS kb-chunk cb of the slab).
// NOTE (r10): h stored fp16-only; own-recurrence stays fp32 in hold[].
// NOTE (r15 postmortem of r11-r14): placement doesn't matter (r13: local
// exchange slower); x-hoist spilled at 128 VGPR (r14: WRITE +304MB =
// 1 dword/thread/step scratch). Step = ~0.7us MFMA + ~0.7us VALU +
// ~3.4us latency stall (gbar RTT + DMA drain). r15 attacks the stall by
// CO-SCHEDULING TWO INDEPENDENT ROW-GROUPS PER CU: 512 blocks x 256 thr
// (4 waves), 2 blocks/CU; bx->(rg,cb) mapped so co-resident blocks
// (bx, bx+256 under standard dispatch) are in ADJACENT groups. Groups'
// barriers are unsynchronized -> one block's stall overlaps the other's
// compute. Data/barrier mechanics are the proven r10 path unchanged.

// LLC-coherent scalar atomics (sc0 sc1: bypass L1/L2, coherent at IF).
__device__ __forceinline__ void sta8(void* p, ull v) {
  __hip_atomic_store((ull*)p, v, __ATOMIC_RELAXED, __HIP_MEMORY_SCOPE_AGENT);
}
__device__ __forceinline__ float lda4f(const float* p) {
  return __hip_atomic_load(p, __ATOMIC_RELAXED, __HIP_MEMORY_SCOPE_AGENT);
}

// ---------------------------------------------------------------------------
// Setup: W_hh (enc,dec) and W_ih (enc) fp32 -> fp16 MFMA-B fragment layout.
// B-frag 16x16x32: lane L holds B[k=(L>>4)*8+t][n=L&15] ->
// W[g*H + jg*16 + (L&15)][kb*32 + (L>>4)*8 + t].
// Chunk c = (((g*64+jg)*32 + kb)*4 + q)*16 + r ; 16B per chunk-lane.
// ---------------------------------------------------------------------------
__global__ void gru_setup(const float* __restrict__ WhhE,
                          const float* __restrict__ WhhD,
                          const float* __restrict__ WihE,
                          char* __restrict__ ws) {
  int t = blockIdx.x * 256 + threadIdx.x;
  if (t < 512) ((unsigned int*)(ws + BARS))[t] = 0u;
  const int NW = 3 * 64 * 32 * 4 * 16;
  if (t < 2 * NW) {
    const float* W = (t < NW) ? WhhE : WhhD;
    size_t dst = (t < NW) ? WF_E : WF_D;
    int c = (t < NW) ? t : t - NW;
    int r = c & 15, q = (c >> 4) & 3, kb = (c >> 6) & 31, gj = c >> 11;
    int row = (gj >> 6) * H_ + (gj & 63) * 16 + r;
    const float* src = W + (size_t)row * H_ + kb * 32 + q * 8;
    half8 v;
#pragma unroll
    for (int i = 0; i < 8; ++i) v[i] = (_Float16)src[i];
    *(half8*)(ws + dst + (size_t)c * 16) = v;
  } else if (t < 2 * NW + 3 * 64 * 2 * 4 * 16) {
    int c = t - 2 * NW;
    int r = c & 15, q = (c >> 4) & 3, kc = (c >> 6) & 1, gj = c >> 7;
    int row = (gj >> 6) * H_ + (gj & 63) * 16 + r;
    const float* src = WihE + (size_t)row * F_ + kc * 32 + q * 8;
    half8 v;
#pragma unroll
    for (int i = 0; i < 8; ++i) v[i] = (_Float16)src[i];
    *(half8*)(ws + WF_I + (size_t)c * 16) = v;
  }
}

// Group barrier: 32 blocks (same rg), own cacheline, relaxed LLC atomics.
// s_sleep in the spin frees the SIMD for the co-resident block.
__device__ __forceinline__ void gbar(unsigned int* cnt, unsigned int target) {
  __syncthreads();
  if (threadIdx.x == 0) {
    __hip_atomic_fetch_add(cnt, 1u, __ATOMIC_RELAXED,
                           __HIP_MEMORY_SCOPE_AGENT);
    while (__hip_atomic_load(cnt, __ATOMIC_RELAXED,
                             __HIP_MEMORY_SCOPE_AGENT) < target)
      __builtin_amdgcn_s_sleep(1);
  }
  __syncthreads();
}

// ---------------------------------------------------------------------------
// Main persistent kernel: 512 blocks x 256 thr (4 waves, 2 blocks/CU).
// bx -> (rg, cb): p=bx>>8, rg=((bx>>4)+p)&15, cb=p*16+(bx&15)  [bijective;
// co-resident pair (bx, bx+256) lands in adjacent groups].
// Block (rg, cb): rows [rg*16,+16), h-cols [cb*32,+32).
// Wave w in [0,4): jp=w&1 (jg=cb*2+jp), kh=w>>1 (K-half); bW = 48 chunks.
// ---------------------------------------------------------------------------
__global__ __launch_bounds__(256, 2) void gru_main(
    const float* __restrict__ x,
    const float* __restrict__ bih_e, const float* __restrict__ bhh_e,
    const float* __restrict__ Wih_d,
    const float* __restrict__ bih_d, const float* __restrict__ bhh_d,
    const float* __restrict__ fcW, const float* __restrict__ fcb,
    float* __restrict__ out, char* __restrict__ ws) {

  __shared__ __align__(128) char atile[32768];  // [kb 32][L 64][16B]
  __shared__ float red[2 * 64 * 17];            // kh1 partials [jp][L][17]
  __shared__ __align__(16) char otile[1024];    // h' image (1KB = kb cb)
  __shared__ float inp_lds[16];

  const int tid = threadIdx.x;
  const int L = tid & 63;
  const int w = tid >> 6;
  const int jp = w & 1;
  const int kh = w >> 1;
  const int bx = blockIdx.x;
  const int p_ = bx >> 8;
  const int rg = ((bx >> 4) + p_) & 15;
  const int cb = p_ * 16 + (bx & 15);
  const int r = L & 15;
  const int q = L >> 4;
  const int jg = cb * 2 + jp;
  const int jc = jg * 16 + r;

  unsigned int* bar = (unsigned int*)(ws + BARS) + (size_t)rg * 32;
  unsigned int bt = 0;

  const size_t slab = (size_t)rg * 32768;

  // zero own h'-region of parity 0 (1KB/block)
  if (tid < 128) {
    sta8(ws + HP + slab + (size_t)cb * 1024 + (size_t)tid * 8, 0ull);
  }

  float hold[4] = {0.f, 0.f, 0.f, 0.f};
  const float fcb_s = *fcb;
  const float fcw_l = fcW[jc];

  bt += 32;
  gbar(bar, bt);

  for (int phase = 0; phase < 2; ++phase) {
    // register-resident W_hh B-frags for (jg, kh): [gate][kk].
    half8 bW[48];
    {
      const char* wf = ws + (phase ? WF_D : WF_E);
#pragma unroll
      for (int g = 0; g < 3; ++g)
#pragma unroll
        for (int kk = 0; kk < 16; ++kk)
          bW[g * 16 + kk] = *(const half8*)(
              wf + (size_t)((g * 64 + jg) * 32 + kh * 16 + kk) * 1024 +
              (size_t)L * 16);
#pragma unroll
      for (int i = 0; i < 48; ++i) asm volatile("" : "+v"(bW[i]));
    }
    const float* bih = phase ? bih_d : bih_e;
    const float* bhh = phase ? bhh_d : bhh_e;
    const float b_r  = bih[jc]          + bhh[jc];
    const float b_z  = bih[H_ + jc]     + bhh[H_ + jc];
    const float b_in = bih[2 * H_ + jc];
    const float b_hn = bhh[2 * H_ + jc];
    float wd_r = 0.f, wd_z = 0.f, wd_n = 0.f;
    if (phase) {
      wd_r = Wih_d[jc]; wd_z = Wih_d[H_ + jc]; wd_n = Wih_d[2 * H_ + jc];
    }

    const int nsteps = phase ? TL_ : T_;
    for (int d = 0; d < nsteps; ++d) {
      const int s = phase ? T_ + d : d;

      // ---- stage A slab (32KB) via async global->LDS DMA, LLC-coherent
      //      (aux 17 = sc0|sc1). 32 segs of 1KB; wave w takes segs
      //      w*8..w*8+7; lane L's 16B lands at seg base + L*16. ----
      {
        const char* srcbase = ws + HP + (size_t)(s & 1) * PSTR + slab;
#pragma unroll
        for (int c = 0; c < 8; ++c) {
          const int seg = w * 8 + c;  // 0..31
          const char* src = srcbase + (size_t)seg * 1024 + (size_t)L * 16;
          __builtin_amdgcn_global_load_lds(
              (const __attribute__((address_space(1))) void*)src,
              (__attribute__((address_space(3))) void*)(atile + seg * 1024),
              16, 0, 17);
        }
      }

      // ---- decoder scalar input (overlaps the staging DMA) ----
      if (phase && tid < 16) {
        float sum = 0.f;
        if (d > 0) {
          const float* pb =
              (const float*)(ws + PB) + (size_t)((d + 1) & 1) * 64 * 256;
          int row = rg * 16 + tid;
          float a = fcb_s;
          for (int jj = 0; jj < 64; ++jj) a += lda4f(&pb[jj * 256 + row]);
          sum = a;
          if (cb == 0) out[(size_t)row * TL_ + (d - 1)] = a;
        }
        inp_lds[tid] = sum;
      }
      __syncthreads();  // drains vmcnt -> DMA complete

      floatx4 a0 = {0.f, 0.f, 0.f, 0.f}, a1 = {0.f, 0.f, 0.f, 0.f};
      floatx4 a2 = {0.f, 0.f, 0.f, 0.f}, aI = {0.f, 0.f, 0.f, 0.f};

      // ---- h-GEMM, this wave's K-half (stride-1 ds_read_b128) ----
#pragma unroll
      for (int kk = 0; kk < 16; ++kk) {
        const int kb = kh * 16 + kk;
        half8 ahi = *(const half8*)(atile + kb * 1024 + L * 16);
        a0 = MFMA(ahi, bW[kk], a0);
        a1 = MFMA(ahi, bW[16 + kk], a1);
        a2 = MFMA(ahi, bW[32 + kk], a2);
      }

      // ---- kh1: encoder x-projection + dump partials ----
      if (kh == 1) {
        if (!phase) {
          const float* xp =
              x + ((size_t)(rg * 16 + r) * T_ + s) * F_ + q * 8;
          const char* wfi = ws + WF_I + (size_t)L * 16;  // L1/L2-hot reloads
#pragma unroll
          for (int kc = 0; kc < 2; ++kc) {
            floatx4 x0 = *(const floatx4*)(xp + kc * 32);
            floatx4 x1 = *(const floatx4*)(xp + kc * 32 + 4);
            half8 xa;
#pragma unroll
            for (int i = 0; i < 4; ++i) {
              xa[i] = (_Float16)x0[i];
              xa[4 + i] = (_Float16)x1[i];
            }
            a0 = MFMA(xa, *(const half8*)(wfi +
                     (size_t)((0 * 64 + jg) * 2 + kc) * 1024), a0);
            a1 = MFMA(xa, *(const half8*)(wfi +
                     (size_t)((1 * 64 + jg) * 2 + kc) * 1024), a1);
            aI = MFMA(xa, *(const half8*)(wfi +
                     (size_t)((2 * 64 + jg) * 2 + kc) * 1024), aI);
          }
        }
        float* rd = &red[(jp * 64 + L) * 17];
#pragma unroll
        for (int i = 0; i < 4; ++i) {
          rd[i] = a0[i];
          rd[4 + i] = a1[i];
          rd[8 + i] = a2[i];
        }
        if (!phase) {
#pragma unroll
          for (int i = 0; i < 4; ++i) rd[12 + i] = aI[i];
        }
      }
      __syncthreads();

      // ---- kh0: reduce halves, gate epilogue, h' -> otile ----
      if (kh == 0) {
        const float* rd = &red[(jp * 64 + L) * 17];
        // otile = slab kb-chunk cb image: offset
        //   ((dlt>>3)&3)*256 + row*16 + (dlt&7)*2, dlt = jp*16+r
        const size_t tbase = (size_t)(jp * 2 + (r >> 3)) * 256 +
                             (size_t)(r & 7) * 2;
        float pv[4];
#pragma unroll
        for (int i = 0; i < 4; ++i) {
          float rpre = a0[i] + rd[i] + b_r;
          float zpre = a1[i] + rd[4 + i] + b_z;
          float hn   = a2[i] + rd[8 + i] + b_hn;
          float inn  = b_in + (phase ? 0.f : rd[12 + i]);
          if (phase) {
            float inp = inp_lds[q * 4 + i];
            rpre += inp * wd_r;
            zpre += inp * wd_z;
            inn  += inp * wd_n;
          }
          float rg_ = 1.f / (1.f + __expf(-rpre));
          float zg = 1.f / (1.f + __expf(-zpre));
          float t2 = __expf(-2.f * (inn + rg_ * hn));
          float ng = 2.f / (1.f + t2) - 1.f;  // tanh, safe at +-inf
          float hnew = (1.f - zg) * ng + zg * hold[i];
          hold[i] = hnew;  // fp32 carry: storage quant never compounds here
          *(_Float16*)(otile + tbase + (size_t)(q * 4 + i) * 16) =
              (_Float16)hnew;
          pv[i] = hnew * fcw_l;
        }
        if (phase) {
#pragma unroll
          for (int i = 0; i < 4; ++i) {
            float v = pv[i];
            v += __shfl_xor(v, 1);
            v += __shfl_xor(v, 2);
            v += __shfl_xor(v, 4);
            v += __shfl_xor(v, 8);
            if (r == 0) {
              float* pb = (float*)(ws + PB) + (size_t)(d & 1) * 64 * 256;
              __hip_atomic_store(&pb[jg * 256 + (rg * 16 + q * 4 + i)], v,
                                 __ATOMIC_RELAXED, __HIP_MEMORY_SCOPE_AGENT);
            }
          }
        }
      }
      __syncthreads();

      // ---- stream h' (1KB) out: coalesced 8B LLC stores ----
      if (tid < 128) {
        ull v = *(const ull*)(otile + (size_t)tid * 8);
        sta8(ws + HP + (size_t)((s + 1) & 1) * PSTR + slab +
                 (size_t)cb * 1024 + (size_t)tid * 8,
             v);
      }

      bt += 32;
      gbar(bar, bt);
    }
  }

  // ---- final output column t = TL-1 ----
  if (cb == 0 && tid < 16) {
    const float* pb =
        (const float*)(ws + PB) + (size_t)((TL_ - 1) & 1) * 64 * 256;
    int row = rg * 16 + tid;
    float a = fcb_s;
    for (int jj = 0; jj < 64; ++jj) a += lda4f(&pb[jj * 256 + row]);
    out[(size_t)row * TL_ + (TL_ - 1)] = a;
  }
}

// ---------------------------------------------------------------------------
extern "C" void kernel_launch(void* const* d_in, const int* in_sizes, int n_in,
                              void* d_out, int out_size, void* d_ws,
                              size_t ws_size, hipStream_t stream) {
  const float* x     = (const float*)d_in[0];
  const float* WihE  = (const float*)d_in[1];
  const float* WhhE  = (const float*)d_in[2];
  const float* bihE  = (const float*)d_in[3];
  const float* bhhE  = (const float*)d_in[4];
  const float* WihD  = (const float*)d_in[5];
  const float* WhhD  = (const float*)d_in[6];
  const float* bihD  = (const float*)d_in[7];
  const float* bhhD  = (const float*)d_in[8];
  const float* fcW   = (const float*)d_in[9];
  const float* fcb   = (const float*)d_in[10];
  float* outp = (float*)d_out;
  char* ws = (char*)d_ws;

  gru_setup<<<3168, 256, 0, stream>>>(WhhE, WhhD, WihE, ws);

  gru_main<<<dim3(512), dim3(256), 0, stream>>>(
      x, bihE, bhhE, WihD, bihD, bhhD, fcW, fcb, outp, ws);
}

// Round 6
// 3994.356 us; speedup vs baseline: 1.3061x; 1.3061x over previous
//
#include <hip/hip_runtime.h>

#define B_  256
#define T_  512
#define F_  64
#define H_  1024
#define TL_ 64

typedef _Float16 half8 __attribute__((ext_vector_type(8)));
typedef float   floatx4 __attribute__((ext_vector_type(4)));
typedef unsigned long long ull;

#define MFMA(a, b, c) __builtin_amdgcn_mfma_f32_16x16x32_f16(a, b, c, 0, 0, 0)

// ws layout (bytes)
#define WF_E   0UL          // W_hh enc fragments: 3*64*32 chunks * 1024B
#define WF_D   6291456UL    // W_hh dec fragments
#define WF_I   12582912UL   // W_ih enc fragments: 3*64*2 chunks * 1024B
#define HP     12976128UL   // h planes: [2 parity][hi fp16 512KB]
#define PSTR   524288UL     // parity stride
#define PB     15073280UL   // fc partials: [2][64 jg][256 rows] f32
#define BARS   15204352UL   // 16 group lines, 128B apart:
//   line[rg] dword 0      : init-barrier counter (gbar, used once)
//   line[rg] dwords 8..23 : per-producer step tags  tgs[cb]
// h plane (fragment-major fp16): [rg 16][kb 32][lane 64][16B]; slab 32KB/rg;
// block (rg,cb) owns the contiguous 2KB at rg*32768 + cb*2048.
// NOTE (r10): h stored fp16-only; own-recurrence stays fp32 in hold[].
// NOTE (r16 postmortem of r11-r15): placement (r13), x-hoist (r14 spill),
// and 2-group co-scheduling (r15: staged bytes doubled -> 1.9x slower) all
// lose. Model: step = staged-byte/latency chain + CENTRAL barrier tail
// (drain -> fetch_add RTT -> all-16 spin -> only then 32KB DMA). r16
// decentralizes: per-producer TAGS (relaxed stores, no RMW). Tag protocol:
// at end of step s, block drains h' stores then sets tgs[cb]=s+1; staging
// chunk j for step s polls tgs[j] >= s and issues that 2KB DMA immediately
// -> straggler wait overlaps early-producer staging; fetch_add RTT gone;
// own chunk copied LDS->LDS from otile (no LLC round trip).
// WAR safety on parity planes: producer overwrites plane p at end of step
// s+1 only after staging s+1 (gated on ALL tags >= s+1, incl. every
// consumer's, set after that consumer finished staging step s). Same
// guarantee as the old barrier, with one step of slack.

// LLC-coherent scalar atomics (sc0 sc1: bypass L1/L2, coherent at IF).
__device__ __forceinline__ void sta8(void* p, ull v) {
  __hip_atomic_store((ull*)p, v, __ATOMIC_RELAXED, __HIP_MEMORY_SCOPE_AGENT);
}
__device__ __forceinline__ void sta4(unsigned* p, unsigned v) {
  __hip_atomic_store(p, v, __ATOMIC_RELAXED, __HIP_MEMORY_SCOPE_AGENT);
}
__device__ __forceinline__ float lda4f(const float* p) {
  return __hip_atomic_load(p, __ATOMIC_RELAXED, __HIP_MEMORY_SCOPE_AGENT);
}
__device__ __forceinline__ unsigned lda4u(const unsigned* p) {
  return __hip_atomic_load(p, __ATOMIC_RELAXED, __HIP_MEMORY_SCOPE_AGENT);
}

// ---------------------------------------------------------------------------
// Setup: W_hh (enc,dec) and W_ih (enc) fp32 -> fp16 MFMA-B fragment layout.
// B-frag 16x16x32: lane L holds B[k=(L>>4)*8+t][n=L&15] ->
// W[g*H + jg*16 + (L&15)][kb*32 + (L>>4)*8 + t].
// Chunk c = (((g*64+jg)*32 + kb)*4 + q)*16 + r ; 16B per chunk-lane.
// ---------------------------------------------------------------------------
__global__ void gru_setup(const float* __restrict__ WhhE,
                          const float* __restrict__ WhhD,
                          const float* __restrict__ WihE,
                          char* __restrict__ ws) {
  int t = blockIdx.x * 256 + threadIdx.x;
  if (t < 512) ((unsigned int*)(ws + BARS))[t] = 0u;   // counters + tags = 0
  const int NW = 3 * 64 * 32 * 4 * 16;
  if (t < 2 * NW) {
    const float* W = (t < NW) ? WhhE : WhhD;
    size_t dst = (t < NW) ? WF_E : WF_D;
    int c = (t < NW) ? t : t - NW;
    int r = c & 15, q = (c >> 4) & 3, kb = (c >> 6) & 31, gj = c >> 11;
    int row = (gj >> 6) * H_ + (gj & 63) * 16 + r;
    const float* src = W + (size_t)row * H_ + kb * 32 + q * 8;
    half8 v;
#pragma unroll
    for (int i = 0; i < 8; ++i) v[i] = (_Float16)src[i];
    *(half8*)(ws + dst + (size_t)c * 16) = v;
  } else if (t < 2 * NW + 3 * 64 * 2 * 4 * 16) {
    int c = t - 2 * NW;
    int r = c & 15, q = (c >> 4) & 3, kc = (c >> 6) & 1, gj = c >> 7;
    int row = (gj >> 6) * H_ + (gj & 63) * 16 + r;
    const float* src = WihE + (size_t)row * F_ + kc * 32 + q * 8;
    half8 v;
#pragma unroll
    for (int i = 0; i < 8; ++i) v[i] = (_Float16)src[i];
    *(half8*)(ws + WF_I + (size_t)c * 16) = v;
  }
}

// Init-only group barrier: 16 blocks (same rg), own cacheline, LLC atomics.
__device__ __forceinline__ void gbar(unsigned int* cnt, unsigned int target) {
  __syncthreads();
  if (threadIdx.x == 0) {
    __hip_atomic_fetch_add(cnt, 1u, __ATOMIC_RELAXED,
                           __HIP_MEMORY_SCOPE_AGENT);
    while (__hip_atomic_load(cnt, __ATOMIC_RELAXED,
                             __HIP_MEMORY_SCOPE_AGENT) < target)
      __builtin_amdgcn_s_sleep(1);
  }
  __syncthreads();
}

// ---------------------------------------------------------------------------
// Main persistent kernel: 256 blocks x 512 thr (8 waves, 1 block/CU) — the
// r10 champion shape. Block (rg=bx&15, cb=bx>>4): rows [rg*16,+16), h-cols
// [cb*64,+64). Wave w: jp=w&3 (jg=cb*4+jp), kh=w>>2; bW = 48 chunks.
// Per-step sync = per-producer tag protocol (see header note); 4
// __syncthreads per step, no atomic RMW, no central spin.
// ---------------------------------------------------------------------------
__global__ __launch_bounds__(512, 2) void gru_main(
    const float* __restrict__ x,
    const float* __restrict__ bih_e, const float* __restrict__ bhh_e,
    const float* __restrict__ Wih_d,
    const float* __restrict__ bih_d, const float* __restrict__ bhh_d,
    const float* __restrict__ fcW, const float* __restrict__ fcb,
    float* __restrict__ out, char* __restrict__ ws) {

  __shared__ __align__(128) char atile[32768];  // [kb 32][L 64][16B]
  __shared__ float red[4 * 64 * 17];            // kh1 partials [jp][L][17]
  __shared__ __align__(16) char otile[2048];    // h' image (2KB)
  __shared__ float inp_lds[16];

  const int tid = threadIdx.x;
  const int L = tid & 63;
  const int w = tid >> 6;
  const int jp = w & 3;
  const int kh = w >> 2;
  const int bx = blockIdx.x;
  const int rg = bx & 15;
  const int cb = bx >> 4;
  const int r = L & 15;
  const int q = L >> 4;
  const int jg = cb * 4 + jp;
  const int jc = jg * 16 + r;

  unsigned int* line = (unsigned int*)(ws + BARS) + (size_t)rg * 32;
  unsigned int* tgs = line + 8;  // 16 per-producer tags

  const size_t slab = (size_t)rg * 32768;

  // zero otile (step-0 own-chunk source) + own h'-region of parity 0
  if (tid < 256) {
    *(ull*)(otile + (size_t)tid * 8) = 0ull;
    sta8(ws + HP + slab + (size_t)cb * 2048 + (size_t)tid * 8, 0ull);
  }

  float hold[4] = {0.f, 0.f, 0.f, 0.f};
  const float fcb_s = *fcb;
  const float fcw_l = fcW[jc];

  // one true barrier: all zeros landed before any step-0 staging
  gbar(line, 16);

  for (int phase = 0; phase < 2; ++phase) {
    // register-resident W_hh B-frags for (jg, kh): [gate][kk].
    half8 bW[48];
    {
      const char* wf = ws + (phase ? WF_D : WF_E);
#pragma unroll
      for (int g = 0; g < 3; ++g)
#pragma unroll
        for (int kk = 0; kk < 16; ++kk)
          bW[g * 16 + kk] = *(const half8*)(
              wf + (size_t)((g * 64 + jg) * 32 + kh * 16 + kk) * 1024 +
              (size_t)L * 16);
#pragma unroll
      for (int i = 0; i < 48; ++i) asm volatile("" : "+v"(bW[i]));
    }
    const float* bih = phase ? bih_d : bih_e;
    const float* bhh = phase ? bhh_d : bhh_e;
    const float b_r  = bih[jc]          + bhh[jc];
    const float b_z  = bih[H_ + jc]     + bhh[H_ + jc];
    const float b_in = bih[2 * H_ + jc];
    const float b_hn = bhh[2 * H_ + jc];
    float wd_r = 0.f, wd_z = 0.f, wd_n = 0.f;
    if (phase) {
      wd_r = Wih_d[jc]; wd_z = Wih_d[H_ + jc]; wd_n = Wih_d[2 * H_ + jc];
    }

    const int nsteps = phase ? TL_ : T_;
    for (int d = 0; d < nsteps; ++d) {
      const int s = phase ? T_ + d : d;
      const unsigned gate = (unsigned)s;

      // ---- tag-gated staging: wave w stages chunks 2w, 2w+1 (2KB each,
      //      producer = block (rg, j)). Poll tgs[j] >= s, then issue the
      //      2 seg DMAs (aux 17, LLC-coherent) immediately — straggler
      //      waits overlap ready-producer staging. Own chunk: LDS copy
      //      from otile (holds h' of step s-1; zeros at s=0). ----
      {
        const char* srcbase = ws + HP + (size_t)(s & 1) * PSTR + slab;
#pragma unroll
        for (int c = 0; c < 2; ++c) {
          const int j = w * 2 + c;
          if (j == cb) {
#pragma unroll
            for (int t2 = 0; t2 < 2; ++t2)
              *(half8*)(atile + (size_t)(j * 2 + t2) * 1024 +
                        (size_t)L * 16) =
                  *(const half8*)(otile + (size_t)t2 * 1024 +
                                  (size_t)L * 16);
          } else {
            while (lda4u(tgs + j) < gate) __builtin_amdgcn_s_sleep(1);
#pragma unroll
            for (int t2 = 0; t2 < 2; ++t2) {
              const int seg = j * 2 + t2;
              const char* src =
                  srcbase + (size_t)seg * 1024 + (size_t)L * 16;
              __builtin_amdgcn_global_load_lds(
                  (const __attribute__((address_space(1))) void*)src,
                  (__attribute__((address_space(3))) void*)(atile +
                                                           seg * 1024),
                  16, 0, 17);
            }
          }
        }
      }

      // ---- decoder scalar input (wave 0 lanes; DMA already issued).
      //      pb(d-1) drained before every producer's tag = s. ----
      if (phase && tid < 16) {
        float sum = 0.f;
        if (d > 0) {
          while (lda4u(tgs + tid) < gate) __builtin_amdgcn_s_sleep(1);
          const float* pb =
              (const float*)(ws + PB) + (size_t)((d + 1) & 1) * 64 * 256;
          int row = rg * 16 + tid;
          float a = fcb_s;
          for (int jj = 0; jj < 64; ++jj) a += lda4f(&pb[jj * 256 + row]);
          sum = a;
          if (cb == 0) out[(size_t)row * TL_ + (d - 1)] = a;
        }
        inp_lds[tid] = sum;
      }
      __syncthreads();  // drains DMA vmcnt; own-copy + inp_lds visible

      floatx4 a0 = {0.f, 0.f, 0.f, 0.f}, a1 = {0.f, 0.f, 0.f, 0.f};
      floatx4 a2 = {0.f, 0.f, 0.f, 0.f}, aI = {0.f, 0.f, 0.f, 0.f};

      // ---- h-GEMM, this wave's K-half (stride-1 ds_read_b128) ----
#pragma unroll
      for (int kk = 0; kk < 16; ++kk) {
        const int kb = kh * 16 + kk;
        half8 ahi = *(const half8*)(atile + kb * 1024 + L * 16);
        a0 = MFMA(ahi, bW[kk], a0);
        a1 = MFMA(ahi, bW[16 + kk], a1);
        a2 = MFMA(ahi, bW[32 + kk], a2);
      }

      // ---- kh1: encoder x-projection + dump partials ----
      if (kh == 1) {
        if (!phase) {
          const float* xp =
              x + ((size_t)(rg * 16 + r) * T_ + s) * F_ + q * 8;
          const char* wfi = ws + WF_I + (size_t)L * 16;  // L1/L2-hot reloads
#pragma unroll
          for (int kc = 0; kc < 2; ++kc) {
            floatx4 x0 = *(const floatx4*)(xp + kc * 32);
            floatx4 x1 = *(const floatx4*)(xp + kc * 32 + 4);
            half8 xa;
#pragma unroll
            for (int i = 0; i < 4; ++i) {
              xa[i] = (_Float16)x0[i];
              xa[4 + i] = (_Float16)x1[i];
            }
            a0 = MFMA(xa, *(const half8*)(wfi +
                     (size_t)((0 * 64 + jg) * 2 + kc) * 1024), a0);
            a1 = MFMA(xa, *(const half8*)(wfi +
                     (size_t)((1 * 64 + jg) * 2 + kc) * 1024), a1);
            aI = MFMA(xa, *(const half8*)(wfi +
                     (size_t)((2 * 64 + jg) * 2 + kc) * 1024), aI);
          }
        }
        float* rd = &red[(jp * 64 + L) * 17];
#pragma unroll
        for (int i = 0; i < 4; ++i) {
          rd[i] = a0[i];
          rd[4 + i] = a1[i];
          rd[8 + i] = a2[i];
        }
        if (!phase) {
#pragma unroll
          for (int i = 0; i < 4; ++i) rd[12 + i] = aI[i];
        }
      }
      __syncthreads();

      // ---- kh0: reduce halves, gate epilogue, h' -> otile ----
      if (kh == 0) {
        const float* rd = &red[(jp * 64 + L) * 17];
        const size_t tbase = (size_t)(jp >> 1) * 1024 +
                             (size_t)((jp & 1) * 2 + (r >> 3)) * 256 +
                             (size_t)(r & 7) * 2;
        float pv[4];
#pragma unroll
        for (int i = 0; i < 4; ++i) {
          float rpre = a0[i] + rd[i] + b_r;
          float zpre = a1[i] + rd[4 + i] + b_z;
          float hn   = a2[i] + rd[8 + i] + b_hn;
          float inn  = b_in + (phase ? 0.f : rd[12 + i]);
          if (phase) {
            float inp = inp_lds[q * 4 + i];
            rpre += inp * wd_r;
            zpre += inp * wd_z;
            inn  += inp * wd_n;
          }
          float rg_ = 1.f / (1.f + __expf(-rpre));
          float zg = 1.f / (1.f + __expf(-zpre));
          float t2 = __expf(-2.f * (inn + rg_ * hn));
          float ng = 2.f / (1.f + t2) - 1.f;  // tanh, safe at +-inf
          float hnew = (1.f - zg) * ng + zg * hold[i];
          hold[i] = hnew;  // fp32 carry: storage quant never compounds here
          *(_Float16*)(otile + tbase + (size_t)(q * 4 + i) * 16) =
              (_Float16)hnew;
          pv[i] = hnew * fcw_l;
        }
        if (phase) {
#pragma unroll
          for (int i = 0; i < 4; ++i) {
            float v = pv[i];
            v += __shfl_xor(v, 1);
            v += __shfl_xor(v, 2);
            v += __shfl_xor(v, 4);
            v += __shfl_xor(v, 8);
            if (r == 0) {
              float* pb = (float*)(ws + PB) + (size_t)(d & 1) * 64 * 256;
              __hip_atomic_store(&pb[jg * 256 + (rg * 16 + q * 4 + i)], v,
                                 __ATOMIC_RELAXED, __HIP_MEMORY_SCOPE_AGENT);
            }
          }
        }
      }
      __syncthreads();

      // ---- stream h' (2KB) out, drain, publish tag s+1 ----
      if (tid < 256) {
        ull v = *(const ull*)(otile + (size_t)tid * 8);
        sta8(ws + HP + (size_t)((s + 1) & 1) * PSTR + slab +
                 (size_t)cb * 2048 + (size_t)tid * 8,
             v);
      }
      __syncthreads();  // every wave's h' (and earlier pb) stores drained
      if (tid == 0) sta4(tgs + cb, (unsigned)(s + 1));
    }
  }

  // ---- final output column t = TL-1 (gate: all producers done) ----
  if (cb == 0 && tid < 16) {
    while (lda4u(tgs + tid) < (unsigned)(T_ + TL_))
      __builtin_amdgcn_s_sleep(1);
    const float* pb =
        (const float*)(ws + PB) + (size_t)((TL_ - 1) & 1) * 64 * 256;
    int row = rg * 16 + tid;
    float a = fcb_s;
    for (int jj = 0; jj < 64; ++jj) a += lda4f(&pb[jj * 256 + row]);
    out[(size_t)row * TL_ + (TL_ - 1)] = a;
  }
}

// ---------------------------------------------------------------------------
extern "C" void kernel_launch(void* const* d_in, const int* in_sizes, int n_in,
                              void* d_out, int out_size, void* d_ws,
                              size_t ws_size, hipStream_t stream) {
  const float* x     = (const float*)d_in[0];
  const float* WihE  = (const float*)d_in[1];
  const float* WhhE  = (const float*)d_in[2];
  const float* bihE  = (const float*)d_in[3];
  const float* bhhE  = (const float*)d_in[4];
  const float* WihD  = (const float*)d_in[5];
  const float* WhhD  = (const float*)d_in[6];
  const float* bihD  = (const float*)d_in[7];
  const float* bhhD  = (const float*)d_in[8];
  const float* fcW   = (const float*)d_in[9];
  const float* fcb   = (const float*)d_in[10];
  float* outp = (float*)d_out;
  char* ws = (char*)d_ws;

  gru_setup<<<3168, 256, 0, stream>>>(WhhE, WhhD, WihE, ws);

  gru_main<<<dim3(256), dim3(512), 0, stream>>>(
      x, bihE, bhhE, WihD, bihD, bhhD, fcW, fcb, outp, ws);
}

// Round 7
// 2604.366 us; speedup vs baseline: 2.0031x; 1.5337x over previous
//
#include <hip/hip_runtime.h>

#define B_  256
#define T_  512
#define F_  64
#define H_  1024
#define TL_ 64

typedef _Float16 half8 __attribute__((ext_vector_type(8)));
typedef float   floatx4 __attribute__((ext_vector_type(4)));
typedef unsigned long long ull;

#define MFMA(a, b, c) __builtin_amdgcn_mfma_f32_16x16x32_f16(a, b, c, 0, 0, 0)

// ws layout (bytes)
#define WF_E   0UL          // W_hh enc fragments: 3*64*32 chunks * 1024B
#define WF_D   6291456UL    // W_hh dec fragments
#define WF_I   12582912UL   // W_ih enc fragments: 3*64*2 chunks * 1024B
#define HP     12976128UL   // h planes: [2 parity][hi fp16 512KB]
#define PSTR   524288UL     // parity stride
#define PB     15073280UL   // fc partials: [2][64 jg][256 rows] f32
#define BARS   15204352UL   // 16 group lines, 128B apart:
//   line[rg] dword 0      : init-barrier counter (gbar, used once)
//   line[rg] dwords 8..23 : per-producer step flags  tgs[cb]
// h plane (fragment-major fp16): [rg 16][kb 32][lane 64][16B]; slab 32KB/rg;
// block (rg,cb) owns the contiguous 2KB at rg*32768 + cb*2048.
// NOTE (r10): h stored fp16-only; own-recurrence stays fp32 in hold[].
// NOTE (r17 postmortem of r11-r16): placement (r13), x-hoist-with-spill
// (r14), 2-groups/CU (r15: staged bytes doubled), per-wave tag polling
// (r16: 16 independent RTT spin chains) all lose to r10. Model: step =
// ~1.3us compute + ~1.1us staging DMA + ~2.3us sync tail (drain -> 16
// SERIALIZED fetch_add RMWs on one LLC line -> spin -> extra syncs).
// r17 keeps r10's central-release protocol and removes the serialized
// hops: (1) flag STORES instead of RMW + ONE 16-lane coalesced poll per
// block (one RTT/iter, __all ballot); (2) h'-store merged into the kh0
// epilogue phase (wave jp owns otile [jp*512,+512) -> wave-local store,
// one syncthreads deleted, stores start earlier); (3) x-proj / decoder
// pb-sum hoisted between DMA-issue and the drain sync (DMA latency
// hidden under atile-independent work).

// LLC-coherent scalar atomics (sc0 sc1: bypass L1/L2, coherent at IF).
__device__ __forceinline__ void sta8(void* p, ull v) {
  __hip_atomic_store((ull*)p, v, __ATOMIC_RELAXED, __HIP_MEMORY_SCOPE_AGENT);
}
__device__ __forceinline__ void sta4(unsigned* p, unsigned v) {
  __hip_atomic_store(p, v, __ATOMIC_RELAXED, __HIP_MEMORY_SCOPE_AGENT);
}
__device__ __forceinline__ float lda4f(const float* p) {
  return __hip_atomic_load(p, __ATOMIC_RELAXED, __HIP_MEMORY_SCOPE_AGENT);
}
__device__ __forceinline__ unsigned lda4u(const unsigned* p) {
  return __hip_atomic_load(p, __ATOMIC_RELAXED, __HIP_MEMORY_SCOPE_AGENT);
}

// ---------------------------------------------------------------------------
// Setup: W_hh (enc,dec) and W_ih (enc) fp32 -> fp16 MFMA-B fragment layout.
// B-frag 16x16x32: lane L holds B[k=(L>>4)*8+t][n=L&15] ->
// W[g*H + jg*16 + (L&15)][kb*32 + (L>>4)*8 + t].
// Chunk c = (((g*64+jg)*32 + kb)*4 + q)*16 + r ; 16B per chunk-lane.
// ---------------------------------------------------------------------------
__global__ void gru_setup(const float* __restrict__ WhhE,
                          const float* __restrict__ WhhD,
                          const float* __restrict__ WihE,
                          char* __restrict__ ws) {
  int t = blockIdx.x * 256 + threadIdx.x;
  if (t < 512) ((unsigned int*)(ws + BARS))[t] = 0u;   // counters + flags = 0
  const int NW = 3 * 64 * 32 * 4 * 16;
  if (t < 2 * NW) {
    const float* W = (t < NW) ? WhhE : WhhD;
    size_t dst = (t < NW) ? WF_E : WF_D;
    int c = (t < NW) ? t : t - NW;
    int r = c & 15, q = (c >> 4) & 3, kb = (c >> 6) & 31, gj = c >> 11;
    int row = (gj >> 6) * H_ + (gj & 63) * 16 + r;
    const float* src = W + (size_t)row * H_ + kb * 32 + q * 8;
    half8 v;
#pragma unroll
    for (int i = 0; i < 8; ++i) v[i] = (_Float16)src[i];
    *(half8*)(ws + dst + (size_t)c * 16) = v;
  } else if (t < 2 * NW + 3 * 64 * 2 * 4 * 16) {
    int c = t - 2 * NW;
    int r = c & 15, q = (c >> 4) & 3, kc = (c >> 6) & 1, gj = c >> 7;
    int row = (gj >> 6) * H_ + (gj & 63) * 16 + r;
    const float* src = WihE + (size_t)row * F_ + kc * 32 + q * 8;
    half8 v;
#pragma unroll
    for (int i = 0; i < 8; ++i) v[i] = (_Float16)src[i];
    *(half8*)(ws + WF_I + (size_t)c * 16) = v;
  }
}

// Init-only group barrier: 16 blocks (same rg), own cacheline, LLC atomics.
__device__ __forceinline__ void gbar(unsigned int* cnt, unsigned int target) {
  __syncthreads();
  if (threadIdx.x == 0) {
    __hip_atomic_fetch_add(cnt, 1u, __ATOMIC_RELAXED,
                           __HIP_MEMORY_SCOPE_AGENT);
    while (__hip_atomic_load(cnt, __ATOMIC_RELAXED,
                             __HIP_MEMORY_SCOPE_AGENT) < target)
      __builtin_amdgcn_s_sleep(1);
  }
  __syncthreads();
}

// ---------------------------------------------------------------------------
// Main persistent kernel: 256 blocks x 512 thr (8 waves, 1 block/CU) — the
// r10 champion shape. Block (rg=bx&15, cb=bx>>4): rows [rg*16,+16), h-cols
// [cb*64,+64). Wave w: jp=w&3 (jg=cb*4+jp), kh=w>>2; bW = 48 chunks.
// Per-step sync: flag stores + one 16-lane coalesced poll (wave 0) +
// syncthreads release. 4 syncthreads/step total.
// ---------------------------------------------------------------------------
__global__ __launch_bounds__(512, 2) void gru_main(
    const float* __restrict__ x,
    const float* __restrict__ bih_e, const float* __restrict__ bhh_e,
    const float* __restrict__ Wih_d,
    const float* __restrict__ bih_d, const float* __restrict__ bhh_d,
    const float* __restrict__ fcW, const float* __restrict__ fcb,
    float* __restrict__ out, char* __restrict__ ws) {

  __shared__ __align__(128) char atile[32768];  // [kb 32][L 64][16B]
  __shared__ float red[4 * 64 * 17];            // kh1 partials [jp][L][17]
  __shared__ __align__(16) char otile[2048];    // h' image (2KB)
  __shared__ float inp_lds[16];

  const int tid = threadIdx.x;
  const int L = tid & 63;
  const int w = tid >> 6;
  const int jp = w & 3;
  const int kh = w >> 2;
  const int bx = blockIdx.x;
  const int rg = bx & 15;
  const int cb = bx >> 4;
  const int r = L & 15;
  const int q = L >> 4;
  const int jg = cb * 4 + jp;
  const int jc = jg * 16 + r;

  unsigned int* line = (unsigned int*)(ws + BARS) + (size_t)rg * 32;
  unsigned int* tgs = line + 8;  // 16 per-producer step flags

  const size_t slab = (size_t)rg * 32768;

  // zero own h'-region of parity 0 (2KB/block)
  if (tid < 256) {
    sta8(ws + HP + slab + (size_t)cb * 2048 + (size_t)tid * 8, 0ull);
  }

  float hold[4] = {0.f, 0.f, 0.f, 0.f};
  const float fcb_s = *fcb;
  const float fcw_l = fcW[jc];

  // one true barrier: all zeros landed before any step-0 staging
  gbar(line, 16);

  for (int phase = 0; phase < 2; ++phase) {
    // register-resident W_hh B-frags for (jg, kh): [gate][kk].
    half8 bW[48];
    {
      const char* wf = ws + (phase ? WF_D : WF_E);
#pragma unroll
      for (int g = 0; g < 3; ++g)
#pragma unroll
        for (int kk = 0; kk < 16; ++kk)
          bW[g * 16 + kk] = *(const half8*)(
              wf + (size_t)((g * 64 + jg) * 32 + kh * 16 + kk) * 1024 +
              (size_t)L * 16);
#pragma unroll
      for (int i = 0; i < 48; ++i) asm volatile("" : "+v"(bW[i]));
    }
    const float* bih = phase ? bih_d : bih_e;
    const float* bhh = phase ? bhh_d : bhh_e;
    const float b_r  = bih[jc]          + bhh[jc];
    const float b_z  = bih[H_ + jc]     + bhh[H_ + jc];
    const float b_in = bih[2 * H_ + jc];
    const float b_hn = bhh[2 * H_ + jc];
    float wd_r = 0.f, wd_z = 0.f, wd_n = 0.f;
    if (phase) {
      wd_r = Wih_d[jc]; wd_z = Wih_d[H_ + jc]; wd_n = Wih_d[2 * H_ + jc];
    }

    const char* wfi = ws + WF_I + (size_t)L * 16;

    const int nsteps = phase ? TL_ : T_;
    for (int d = 0; d < nsteps; ++d) {
      const int s = phase ? T_ + d : d;
      const unsigned tnext = (unsigned)(s + 1);

      // ---- A: stage A slab (32KB) via async global->LDS DMA, aux 17
      //      (sc0|sc1, LLC-coherent). 32 segs of 1KB; wave w takes segs
      //      w*4..w*4+3; lane L's 16B lands at seg base + L*16. ----
      {
        const char* srcbase = ws + HP + (size_t)(s & 1) * PSTR + slab;
#pragma unroll
        for (int c = 0; c < 4; ++c) {
          const int seg = w * 4 + c;  // 0..31
          const char* src = srcbase + (size_t)seg * 1024 + (size_t)L * 16;
          __builtin_amdgcn_global_load_lds(
              (const __attribute__((address_space(1))) void*)src,
              (__attribute__((address_space(3))) void*)(atile + seg * 1024),
              16, 0, 17);
        }
      }

      // ---- B: atile-independent work overlaps the DMA latency ----
      // enc kh1: x-projection into a0,a1,aI (x + W_ih only)
      floatx4 a0 = {0.f, 0.f, 0.f, 0.f}, a1 = {0.f, 0.f, 0.f, 0.f};
      floatx4 aI = {0.f, 0.f, 0.f, 0.f};
      if (!phase && kh == 1) {
        const float* xp = x + ((size_t)(rg * 16 + r) * T_ + s) * F_ + q * 8;
#pragma unroll
        for (int kc = 0; kc < 2; ++kc) {
          floatx4 x0 = *(const floatx4*)(xp + kc * 32);
          floatx4 x1 = *(const floatx4*)(xp + kc * 32 + 4);
          half8 xa;
#pragma unroll
          for (int i = 0; i < 4; ++i) {
            xa[i] = (_Float16)x0[i];
            xa[4 + i] = (_Float16)x1[i];
          }
          a0 = MFMA(xa, *(const half8*)(wfi +
                   (size_t)((0 * 64 + jg) * 2 + kc) * 1024), a0);
          a1 = MFMA(xa, *(const half8*)(wfi +
                   (size_t)((1 * 64 + jg) * 2 + kc) * 1024), a1);
          aI = MFMA(xa, *(const half8*)(wfi +
                   (size_t)((2 * 64 + jg) * 2 + kc) * 1024), aI);
        }
      }
      // dec: scalar input gather (pb(d-1) guaranteed by the step-(s-1)
      // barrier: all flags >= s implies all pb stores drained)
      if (phase && tid < 16) {
        float sum = 0.f;
        if (d > 0) {
          const float* pb =
              (const float*)(ws + PB) + (size_t)((d + 1) & 1) * 64 * 256;
          int row = rg * 16 + tid;
          float a = fcb_s;
          for (int jj = 0; jj < 64; ++jj) a += lda4f(&pb[jj * 256 + row]);
          sum = a;
          if (cb == 0) out[(size_t)row * TL_ + (d - 1)] = a;
        }
        inp_lds[tid] = sum;
      }
      __syncthreads();  // C: drains vmcnt -> staging DMA complete

      floatx4 a2 = {0.f, 0.f, 0.f, 0.f};

      // ---- D: h-GEMM, this wave's K-half (stride-1 ds_read_b128);
      //      kh1-enc accumulates on top of the hoisted x-projection ----
#pragma unroll
      for (int kk = 0; kk < 16; ++kk) {
        const int kb = kh * 16 + kk;
        half8 ahi = *(const half8*)(atile + kb * 1024 + L * 16);
        a0 = MFMA(ahi, bW[kk], a0);
        a1 = MFMA(ahi, bW[16 + kk], a1);
        a2 = MFMA(ahi, bW[32 + kk], a2);
      }

      // ---- E: kh1 dumps partials ----
      if (kh == 1) {
        float* rd = &red[(jp * 64 + L) * 17];
#pragma unroll
        for (int i = 0; i < 4; ++i) {
          rd[i] = a0[i];
          rd[4 + i] = a1[i];
          rd[8 + i] = a2[i];
        }
        if (!phase) {
#pragma unroll
          for (int i = 0; i < 4; ++i) rd[12 + i] = aI[i];
        }
      }
      __syncthreads();

      // ---- F: kh0 reduce halves + gate epilogue -> otile; then wave jp
      //      stores ITS OWN otile 512B [jp*512,+512) to the global plane
      //      (wave-local lgkmcnt ordering; no cross-wave sync needed) ----
      if (kh == 0) {
        const float* rd = &red[(jp * 64 + L) * 17];
        const size_t tbase = (size_t)(jp >> 1) * 1024 +
                             (size_t)((jp & 1) * 2 + (r >> 3)) * 256 +
                             (size_t)(r & 7) * 2;
        float pv[4];
#pragma unroll
        for (int i = 0; i < 4; ++i) {
          float rpre = a0[i] + rd[i] + b_r;
          float zpre = a1[i] + rd[4 + i] + b_z;
          float hn   = a2[i] + rd[8 + i] + b_hn;
          float inn  = b_in + (phase ? 0.f : rd[12 + i]);
          if (phase) {
            float inp = inp_lds[q * 4 + i];
            rpre += inp * wd_r;
            zpre += inp * wd_z;
            inn  += inp * wd_n;
          }
          float rg_ = 1.f / (1.f + __expf(-rpre));
          float zg = 1.f / (1.f + __expf(-zpre));
          float t2 = __expf(-2.f * (inn + rg_ * hn));
          float ng = 2.f / (1.f + t2) - 1.f;  // tanh, safe at +-inf
          float hnew = (1.f - zg) * ng + zg * hold[i];
          hold[i] = hnew;  // fp32 carry: storage quant never compounds here
          *(_Float16*)(otile + tbase + (size_t)(q * 4 + i) * 16) =
              (_Float16)hnew;
          pv[i] = hnew * fcw_l;
        }
        if (phase) {
#pragma unroll
          for (int i = 0; i < 4; ++i) {
            float v = pv[i];
            v += __shfl_xor(v, 1);
            v += __shfl_xor(v, 2);
            v += __shfl_xor(v, 4);
            v += __shfl_xor(v, 8);
            if (r == 0) {
              float* pb = (float*)(ws + PB) + (size_t)(d & 1) * 64 * 256;
              __hip_atomic_store(&pb[jg * 256 + (rg * 16 + q * 4 + i)], v,
                                 __ATOMIC_RELAXED, __HIP_MEMORY_SCOPE_AGENT);
            }
          }
        }
        // own 512B of h' image -> plane ((s+1)&1), coalesced 8B stores
        ull v8 = *(const ull*)(otile + (size_t)jp * 512 + (size_t)L * 8);
        sta8(ws + HP + (size_t)((s + 1) & 1) * PSTR + slab +
                 (size_t)cb * 2048 + (size_t)jp * 512 + (size_t)L * 8,
             v8);
      }

      // ---- G/H/I/J: drain -> publish flag -> coalesced poll -> release --
      __syncthreads();  // every wave drained its vmcnt before s_barrier
      if (tid == 0) sta4(tgs + cb, tnext);
      if (w == 0) {
        for (;;) {
          unsigned tag = (L < 16) ? lda4u(tgs + L) : tnext;
          if (__all((int)(tag >= tnext))) break;
          __builtin_amdgcn_s_sleep(1);
        }
      }
      __syncthreads();
    }
  }

  // ---- final output column t = TL-1 (all flags = T_+TL_ after the loop) --
  if (cb == 0 && tid < 16) {
    const float* pb =
        (const float*)(ws + PB) + (size_t)((TL_ - 1) & 1) * 64 * 256;
    int row = rg * 16 + tid;
    float a = fcb_s;
    for (int jj = 0; jj < 64; ++jj) a += lda4f(&pb[jj * 256 + row]);
    out[(size_t)row * TL_ + (TL_ - 1)] = a;
  }
}

// ---------------------------------------------------------------------------
extern "C" void kernel_launch(void* const* d_in, const int* in_sizes, int n_in,
                              void* d_out, int out_size, void* d_ws,
                              size_t ws_size, hipStream_t stream) {
  const float* x     = (const float*)d_in[0];
  const float* WihE  = (const float*)d_in[1];
  const float* WhhE  = (const float*)d_in[2];
  const float* bihE  = (const float*)d_in[3];
  const float* bhhE  = (const float*)d_in[4];
  const float* WihD  = (const float*)d_in[5];
  const float* WhhD  = (const float*)d_in[6];
  const float* bihD  = (const float*)d_in[7];
  const float* bhhD  = (const float*)d_in[8];
  const float* fcW   = (const float*)d_in[9];
  const float* fcb   = (const float*)d_in[10];
  float* outp = (float*)d_out;
  char* ws = (char*)d_ws;

  gru_setup<<<3168, 256, 0, stream>>>(WhhE, WhhD, WihE, ws);

  gru_main<<<dim3(256), dim3(512), 0, stream>>>(
      x, bihE, bhhE, WihD, bihD, bhhD, fcW, fcb, outp, ws);
}